// Round 10
// baseline (357.953 us; speedup 1.0000x reference)
//
#include <hip/hip_runtime.h>
#include <hip/hip_bf16.h>
#include <hip/hip_fp16.h>
#include <math.h>

#define N_NODES 50000
#define N_EDGES 800000
#define IN_DIM 128
#define NHEAD 4
#define NREL 64
#define HC 256              // NHEAD * 64 (both layers: H*HID = H*OUT = 256)
#define NEG_SLOPE 0.2f
#define SCAN_B ((N_NODES + 255) / 256)   // 196 blocks
#define PAD_X 65            // xlds row pad (floats)

// ============ GEMM + fused alpha, 64x128 tile, 8x4/thread, reg-staged prefetch ===
// __launch_bounds__(256,4): min 4 waves/EU -> VGPR cap 128, so the prefetch
// buffers (24 regs) + acc (32) stay in registers. R9's default cap (64) spilled
// them to scratch: WRITE_SIZE 28->100 MB. This declaration is the fix.
__global__ __launch_bounds__(256, 4) void gemm_xw_alpha(
    const float* __restrict__ X, const float* __restrict__ W,
    const float* __restrict__ a_s, const float* __restrict__ a_d,
    __half2* __restrict__ xs16, float* __restrict__ asrc, float* __restrict__ adst,
    int M, int K) {
  __shared__ __align__(16) float xlds[32][PAD_X];  // [kk][row]  8.3 KB
  __shared__ __align__(16) float wlds[32][128];    // [kk][col] 16.4 KB
  const int t = threadIdx.x;
  const int wv = t >> 6;
  const int l  = t & 63;
  const int rg = l >> 5;                  // row-half within wave
  const int cg = l & 31;                  // col-group
  const int cc = cg * 4;                  // local col
  const int rbase = wv * 16 + rg * 8;     // local row base (8 rows/thread)
  const int row0 = blockIdx.x * 64;
  const int c0 = blockIdx.y * 128;

  // staging roles
  const int sx_row = t >> 2;              // 0..63
  const int sx_k   = (t & 3) * 4;         // {0,4,8,12}; second load at +16
  const int sw_k   = t >> 5;              // 0..7; planes sw_k + p*8
  const int sw_c   = (t & 31) * 4;

  const int srow = row0 + sx_row;
  const bool sok = srow < M;
  const float* Xr = &X[(size_t)srow * K];

  float4 xbuf0, xbuf1, wbuf[4];
  // ---- prologue: load tile kb=0 into registers ----
  xbuf0 = sok ? *(const float4*)&Xr[sx_k]      : make_float4(0.f, 0.f, 0.f, 0.f);
  xbuf1 = sok ? *(const float4*)&Xr[sx_k + 16] : make_float4(0.f, 0.f, 0.f, 0.f);
#pragma unroll
  for (int p = 0; p < 4; ++p)
    wbuf[p] = *(const float4*)&W[(size_t)(sw_k + p * 8) * HC + c0 + sw_c];

  float acc[8][4];
#pragma unroll
  for (int r = 0; r < 8; ++r)
#pragma unroll
    for (int c = 0; c < 4; ++c) acc[r][c] = 0.f;

  for (int kb = 0; kb < K; kb += 32) {
    __syncthreads();                      // previous tile's consumers done
    // regs -> LDS
    xlds[sx_k + 0][sx_row] = xbuf0.x;
    xlds[sx_k + 1][sx_row] = xbuf0.y;
    xlds[sx_k + 2][sx_row] = xbuf0.z;
    xlds[sx_k + 3][sx_row] = xbuf0.w;
    xlds[sx_k + 16][sx_row] = xbuf1.x;
    xlds[sx_k + 17][sx_row] = xbuf1.y;
    xlds[sx_k + 18][sx_row] = xbuf1.z;
    xlds[sx_k + 19][sx_row] = xbuf1.w;
#pragma unroll
    for (int p = 0; p < 4; ++p)
      *(float4*)&wlds[sw_k + p * 8][sw_c] = wbuf[p];
    __syncthreads();                      // tile kb visible
    // issue next tile's loads (overlap with compute below)
    if (kb + 32 < K) {
      xbuf0 = sok ? *(const float4*)&Xr[kb + 32 + sx_k]      : make_float4(0.f, 0.f, 0.f, 0.f);
      xbuf1 = sok ? *(const float4*)&Xr[kb + 32 + sx_k + 16] : make_float4(0.f, 0.f, 0.f, 0.f);
#pragma unroll
      for (int p = 0; p < 4; ++p)
        wbuf[p] = *(const float4*)&W[(size_t)(kb + 32 + sw_k + p * 8) * HC + c0 + sw_c];
    }
    // compute tile kb
#pragma unroll 8
    for (int kk = 0; kk < 32; ++kk) {
      const float4 w4 = *(const float4*)&wlds[kk][cc];
      const float4 xa = *(const float4*)&xlds[kk][rbase];
      const float4 xb = *(const float4*)&xlds[kk][rbase + 4];
      const float xr[8] = {xa.x, xa.y, xa.z, xa.w, xb.x, xb.y, xb.z, xb.w};
#pragma unroll
      for (int r = 0; r < 8; ++r) {
        acc[r][0] += xr[r] * w4.x;
        acc[r][1] += xr[r] * w4.y;
        acc[r][2] += xr[r] * w4.z;
        acc[r][3] += xr[r] * w4.w;
      }
    }
  }

  const float4 as4 = *(const float4*)&a_s[c0 + cc];
  const float4 ad4 = *(const float4*)&a_d[c0 + cc];
  const int head = blockIdx.y * 2 + (cg >> 4);
#pragma unroll
  for (int r = 0; r < 8; ++r) {
    const int row = row0 + rbase + r;
    const bool ok = row < M;
    if (ok) {
      __half2 q0 = __floats2half2_rn(acc[r][0], acc[r][1]);
      __half2 q1 = __floats2half2_rn(acc[r][2], acc[r][3]);
      uint2 qq = make_uint2(*(unsigned*)&q0, *(unsigned*)&q1);
      *(uint2*)&xs16[((size_t)row * HC + c0 + cc) >> 1] = qq;
    }
    float sp = acc[r][0] * as4.x + acc[r][1] * as4.y + acc[r][2] * as4.z + acc[r][3] * as4.w;
    float dp = acc[r][0] * ad4.x + acc[r][1] * ad4.y + acc[r][2] * ad4.z + acc[r][3] * ad4.w;
#pragma unroll
    for (int off = 1; off < 16; off <<= 1) {
      sp += __shfl_xor(sp, off);
      dp += __shfl_xor(dp, off);
    }
    if ((cg & 15) == 0 && ok) {
      asrc[row * NHEAD + head] = sp;
      adst[row * NHEAD + head] = dp;
    }
  }
}

// ============ per-relation alpha_e tables for BOTH layers ============
__global__ __launch_bounds__(256) void relalpha2_kernel(
    const float* __restrict__ rel1, const float* __restrict__ We1, const float* __restrict__ ae1,
    const float* __restrict__ rel2, const float* __restrict__ We2, const float* __restrict__ ae2,
    float* __restrict__ tab1, float* __restrict__ tab2) {
  const int layer = blockIdx.x >> 6;
  const int r = blockIdx.x & 63;
  const float* rel = layer ? rel2 : rel1;
  const float* We  = layer ? We2  : We1;
  const float* ae  = layer ? ae2  : ae1;
  float* tab       = layer ? tab2 : tab1;
  const int K      = layer ? 64   : IN_DIM;
  int t = threadIdx.x;
  float acc = 0.f;
  for (int k = 0; k < K; ++k) acc += rel[(size_t)r * K + k] * We[(size_t)k * HC + t];
  int h = t >> 6, lane = t & 63;
  float p = acc * ae[t];
#pragma unroll
  for (int off = 32; off > 0; off >>= 1) p += __shfl_down(p, off);
  if (lane == 0) tab[r * NHEAD + h] = p;
}

// ============ CSR build ============
__global__ __launch_bounds__(256) void hist_kernel(
    const int* __restrict__ dst, int* __restrict__ deg) {
  int e = blockIdx.x * blockDim.x + threadIdx.x;
  if (e < N_EDGES) atomicAdd(&deg[dst[e]], 1);
}

__global__ __launch_bounds__(256) void block_sum_kernel(
    const int* __restrict__ deg, int* __restrict__ bsum) {
  int i = blockIdx.x * 256 + threadIdx.x;
  int v = (i < N_NODES) ? deg[i] : 0;
#pragma unroll
  for (int off = 32; off > 0; off >>= 1) v += __shfl_down(v, off);
  __shared__ int w[4];
  if ((threadIdx.x & 63) == 0) w[threadIdx.x >> 6] = v;
  __syncthreads();
  if (threadIdx.x == 0) bsum[blockIdx.x] = w[0] + w[1] + w[2] + w[3];
}

__global__ __launch_bounds__(256) void scan_bsum_kernel(
    const int* __restrict__ bsum, int* __restrict__ boff) {
  __shared__ int s[256];
  int t = threadIdx.x;
  int v = (t < SCAN_B) ? bsum[t] : 0;
  s[t] = v;
  __syncthreads();
  for (int off = 1; off < 256; off <<= 1) {
    int u = (t >= off) ? s[t - off] : 0;
    __syncthreads();
    s[t] += u;
    __syncthreads();
  }
  boff[t] = (t == 0) ? 0 : s[t - 1];
}

__global__ __launch_bounds__(256) void scan_final_kernel(
    const int* __restrict__ deg, const int* __restrict__ boff,
    int* __restrict__ rowptr, int* __restrict__ cursor) {
  __shared__ int s[256];
  int t = threadIdx.x;
  int i = blockIdx.x * 256 + t;
  int v = (i < N_NODES) ? deg[i] : 0;
  s[t] = v;
  __syncthreads();
  for (int off = 1; off < 256; off <<= 1) {
    int u = (t >= off) ? s[t - off] : 0;
    __syncthreads();
    s[t] += u;
    __syncthreads();
  }
  int excl = boff[blockIdx.x] + s[t] - v;
  if (i < N_NODES) {
    rowptr[i] = excl;
    cursor[i] = excl;
  }
  if (t == 0 && blockIdx.x == 0) rowptr[N_NODES] = N_EDGES;
}

__global__ __launch_bounds__(256) void fill_kernel(
    const int* __restrict__ src, const int* __restrict__ dst,
    const int* __restrict__ etype, int* __restrict__ cursor,
    int2* __restrict__ csr_pack) {
  int e = blockIdx.x * blockDim.x + threadIdx.x;
  if (e >= N_EDGES) return;
  int d = dst[e];
  int i = atomicAdd(&cursor[d], 1);
  csr_pack[i] = make_int2(src[e], etype[e]);
}

// ============ fused no-max softmax + fp16 gather: ONE WAVE PER NODE ============
__global__ __launch_bounds__(256) void gat_node_kernel(
    const int* __restrict__ rowptr, const int2* __restrict__ csr,
    const float* __restrict__ asrc, const float* __restrict__ adst,
    const float* __restrict__ tab, const __half2* __restrict__ xs16,
    const float* __restrict__ b, float* __restrict__ out, int relu) {
  const int n = (blockIdx.x * blockDim.x + threadIdx.x) >> 6;
  if (n >= N_NODES) return;
  const int lane = threadIdx.x & 63;
  const int hh = lane >> 4;               // head of this lane's 4 cols
  const int cbase = lane << 2;
  const int i0 = rowptr[n], i1 = rowptr[n + 1];
  const float adn = adst[n * NHEAD + hh];
  const float treg = tab[lane * NHEAD + hh];   // lane = rel id (NREL==64)

  float4 acc = make_float4(0.f, 0.f, 0.f, 0.f);
  float den = 0.f;
  int i = i0;
  for (; i + 4 <= i1; i += 4) {
    const int2 p0 = csr[i], p1 = csr[i + 1], p2 = csr[i + 2], p3 = csr[i + 3];
    float l0 = asrc[p0.x * NHEAD + hh] + adn + __shfl(treg, p0.y);
    float l1 = asrc[p1.x * NHEAD + hh] + adn + __shfl(treg, p1.y);
    float l2 = asrc[p2.x * NHEAD + hh] + adn + __shfl(treg, p2.y);
    float l3 = asrc[p3.x * NHEAD + hh] + adn + __shfl(treg, p3.y);
    const uint2 q0 = *(const uint2*)&xs16[((size_t)p0.x * HC + cbase) >> 1];
    const uint2 q1 = *(const uint2*)&xs16[((size_t)p1.x * HC + cbase) >> 1];
    const uint2 q2 = *(const uint2*)&xs16[((size_t)p2.x * HC + cbase) >> 1];
    const uint2 q3 = *(const uint2*)&xs16[((size_t)p3.x * HC + cbase) >> 1];
    l0 = (l0 >= 0.f) ? l0 : NEG_SLOPE * l0;
    l1 = (l1 >= 0.f) ? l1 : NEG_SLOPE * l1;
    l2 = (l2 >= 0.f) ? l2 : NEG_SLOPE * l2;
    l3 = (l3 >= 0.f) ? l3 : NEG_SLOPE * l3;
    const float w0 = __expf(l0), w1 = __expf(l1), w2 = __expf(l2), w3 = __expf(l3);
    den += (w0 + w1) + (w2 + w3);
    const float2 a0 = __half22float2(*(const __half2*)&q0.x), b0 = __half22float2(*(const __half2*)&q0.y);
    const float2 a1 = __half22float2(*(const __half2*)&q1.x), b1 = __half22float2(*(const __half2*)&q1.y);
    const float2 a2 = __half22float2(*(const __half2*)&q2.x), b2 = __half22float2(*(const __half2*)&q2.y);
    const float2 a3 = __half22float2(*(const __half2*)&q3.x), b3 = __half22float2(*(const __half2*)&q3.y);
    acc.x += w0 * a0.x + w1 * a1.x + w2 * a2.x + w3 * a3.x;
    acc.y += w0 * a0.y + w1 * a1.y + w2 * a2.y + w3 * a3.y;
    acc.z += w0 * b0.x + w1 * b1.x + w2 * b2.x + w3 * b3.x;
    acc.w += w0 * b0.y + w1 * b1.y + w2 * b2.y + w3 * b3.y;
  }
  for (; i < i1; ++i) {
    const int2 p = csr[i];
    float l = asrc[p.x * NHEAD + hh] + adn + __shfl(treg, p.y);
    l = (l >= 0.f) ? l : NEG_SLOPE * l;
    const float w = __expf(l);
    const uint2 q = *(const uint2*)&xs16[((size_t)p.x * HC + cbase) >> 1];
    const float2 a = __half22float2(*(const __half2*)&q.x);
    const float2 c = __half22float2(*(const __half2*)&q.y);
    den += w;
    acc.x += w * a.x; acc.y += w * a.y; acc.z += w * c.x; acc.w += w * c.y;
  }

  const float rd = (den > 0.f) ? (0.25f / den) : 0.f;
  float4 y = make_float4(acc.x * rd, acc.y * rd, acc.z * rd, acc.w * rd);
#pragma unroll
  for (int off = 16; off < 64; off <<= 1) {
    y.x += __shfl_xor(y.x, off);
    y.y += __shfl_xor(y.y, off);
    y.z += __shfl_xor(y.z, off);
    y.w += __shfl_xor(y.w, off);
  }
  if (lane < 16) {
    const float4 bb = *(const float4*)&b[lane * 4];
    y.x += bb.x; y.y += bb.y; y.z += bb.z; y.w += bb.w;
    if (relu) {
      y.x = fmaxf(y.x, 0.f); y.y = fmaxf(y.y, 0.f);
      y.z = fmaxf(y.z, 0.f); y.w = fmaxf(y.w, 0.f);
    }
    *(float4*)&out[(size_t)n * 64 + lane * 4] = y;
  }
}

extern "C" void kernel_launch(void* const* d_in, const int* in_sizes, int n_in,
                              void* d_out, int out_size, void* d_ws, size_t ws_size,
                              hipStream_t stream) {
  const float* x   = (const float*)d_in[0];
  const int* eidx  = (const int*)d_in[1];
  const int* etype = (const int*)d_in[2];
  const float* rel1 = (const float*)d_in[3];
  const float* W1   = (const float*)d_in[4];
  const float* We1  = (const float*)d_in[5];
  const float* as1  = (const float*)d_in[6];
  const float* ad1  = (const float*)d_in[7];
  const float* ae1  = (const float*)d_in[8];
  const float* b1   = (const float*)d_in[9];
  const float* rel2 = (const float*)d_in[10];
  const float* W2   = (const float*)d_in[11];
  const float* We2  = (const float*)d_in[12];
  const float* as2  = (const float*)d_in[13];
  const float* ad2  = (const float*)d_in[14];
  const float* ae2  = (const float*)d_in[15];
  const float* b2   = (const float*)d_in[16];
  const int* src = eidx;
  const int* dst = eidx + N_EDGES;

  // ---- workspace layout ----
  __half2* xs16 = (__half2*)d_ws;                         // N*256 halves
  float* fbase = (float*)((char*)d_ws + (size_t)N_NODES * HC * 2);
  float* asrc = fbase;                                    // N*4
  float* adst = asrc + (size_t)N_NODES * NHEAD;           // N*4
  float* tab1 = adst + (size_t)N_NODES * NHEAD;           // R*4
  float* tab2 = tab1 + NREL * NHEAD;                      // R*4
  float* h1   = tab2 + NREL * NHEAD;                      // N*64
  int* ip = (int*)(h1 + (size_t)N_NODES * 64);
  int* deg     = ip;                                      // N
  int* rowptr  = deg + N_NODES;                           // N+1
  int* cursor  = rowptr + N_NODES + 1;                    // N
  int2* csr    = (int2*)(cursor + N_NODES + 1);           // E int2
  int* bsum    = (int*)(csr + N_EDGES);                   // 256
  int* boff    = bsum + 256;                              // 256

  // ---- CSR build + both alpha_e tables (layer-independent) ----
  hipMemsetAsync(deg, 0, N_NODES * sizeof(int), stream);
  hist_kernel<<<(N_EDGES + 255) / 256, 256, 0, stream>>>(dst, deg);
  block_sum_kernel<<<SCAN_B, 256, 0, stream>>>(deg, bsum);
  scan_bsum_kernel<<<1, 256, 0, stream>>>(bsum, boff);
  scan_final_kernel<<<SCAN_B, 256, 0, stream>>>(deg, boff, rowptr, cursor);
  fill_kernel<<<(N_EDGES + 255) / 256, 256, 0, stream>>>(src, dst, etype, cursor, csr);
  relalpha2_kernel<<<2 * NREL, 256, 0, stream>>>(rel1, We1, ae1, rel2, We2, ae2, tab1, tab2);

  const dim3 gemm_grid((N_NODES + 63) / 64, 2);
  const int GB = (N_NODES * 64 + 255) / 256;   // one wave per node

  // ================= layer 1 =================
  gemm_xw_alpha<<<gemm_grid, 256, 0, stream>>>(x, W1, as1, ad1, xs16, asrc, adst, N_NODES, IN_DIM);
  gat_node_kernel<<<GB, 256, 0, stream>>>(rowptr, csr, asrc, adst, tab1, xs16, b1, h1, 1);

  // ================= layer 2 =================
  gemm_xw_alpha<<<gemm_grid, 256, 0, stream>>>(h1, W2, as2, ad2, xs16, asrc, adst, N_NODES, 64);
  gat_node_kernel<<<GB, 256, 0, stream>>>(rowptr, csr, asrc, adst, tab2, xs16, b2, (float*)d_out, 0);
}

// Round 11
// 348.200 us; speedup vs baseline: 1.0280x; 1.0280x over previous
//
#include <hip/hip_runtime.h>
#include <hip/hip_bf16.h>
#include <hip/hip_fp16.h>
#include <math.h>

#define N_NODES 50000
#define N_EDGES 800000
#define IN_DIM 128
#define NHEAD 4
#define NREL 64
#define HC 256              // NHEAD * 64 (both layers: H*HID = H*OUT = 256)
#define NEG_SLOPE 0.2f
#define SCAN_B ((N_NODES + 255) / 256)   // 196 blocks

// async global->LDS, 16B per lane (zero VGPR staging; compiler never auto-emits)
__device__ __forceinline__ void load_lds16(const float* g, float* l) {
  __builtin_amdgcn_global_load_lds(
      (const __attribute__((address_space(1))) unsigned int*)g,
      (__attribute__((address_space(3))) unsigned int*)l, 16, 0, 0);
}

// ============ GEMM + fused alpha, 64x128 tile, 8x4/thread ============
// Staging via global_load_lds into double-buffered LDS; counted vmcnt(6)
// (= 6 global_load_lds instrs/wave/stage) + raw s_barrier keeps next tile's
// loads in flight across the barrier. No staging registers -> no spill
// (R9/R10: compiler capped at 60 VGPR and spilled reg-prefetch to scratch,
// WRITE_SIZE 28->100 MB; launch_bounds can only cap regs, not raise them).
__global__ __launch_bounds__(256) void gemm_xw_alpha(
    const float* __restrict__ X, const float* __restrict__ W,
    const float* __restrict__ a_s, const float* __restrict__ a_d,
    __half2* __restrict__ xs16, float* __restrict__ asrc, float* __restrict__ adst,
    int M, int K) {
  __shared__ __align__(16) float wbuf[2][32][128];   // [buf][kk][col] 16KB each
  __shared__ __align__(16) float xbuf[2][64][32];    // [buf][row][kk]  8KB each
  const int t = threadIdx.x;
  const int wv = t >> 6;
  const int l  = t & 63;
  const int rg = l >> 5;                  // row-half within wave
  const int cg = l & 31;                  // col-group
  const int cc = cg * 4;                  // local col
  const int rbase = wv * 16 + rg * 8;     // local row base (8 rows/thread)
  const int row0 = blockIdx.x * 64;
  const int c0 = blockIdx.y * 128;

#define STAGE(BI, KB)                                                          \
  {                                                                            \
    _Pragma("unroll")                                                          \
    for (int j = 0; j < 4; ++j) {                                              \
      const int wrow = wv * 8 + j * 2 + (l >> 5);                              \
      load_lds16(&W[(size_t)((KB) + wrow) * HC + c0 + (l & 31) * 4],           \
                 &wbuf[BI][wv * 8 + j * 2][0]);                                \
    }                                                                          \
    _Pragma("unroll")                                                          \
    for (int j = 0; j < 2; ++j) {                                              \
      const int xrow = wv * 16 + j * 8 + (l >> 3);                             \
      const int grow = min(row0 + xrow, M - 1);                                \
      load_lds16(&X[(size_t)grow * K + (KB) + (l & 7) * 4],                    \
                 &xbuf[BI][wv * 16 + j * 8][0]);                               \
    }                                                                          \
  }

  float acc[8][4];
#pragma unroll
  for (int r = 0; r < 8; ++r)
#pragma unroll
    for (int c = 0; c < 4; ++c) acc[r][c] = 0.f;

  STAGE(0, 0);                            // prologue: tile 0 in flight
  const int nt = K >> 5;
  for (int tg = 0; tg < nt; ++tg) {
    const int cur = tg & 1;
    if (tg + 1 < nt) {
      STAGE(cur ^ 1, (tg + 1) * 32);      // issue next tile (async)
      asm volatile("s_waitcnt vmcnt(6)" ::: "memory");   // this tile landed
    } else {
      asm volatile("s_waitcnt vmcnt(0)" ::: "memory");
    }
    __builtin_amdgcn_s_barrier();         // all waves' tile-tg loads visible
    __builtin_amdgcn_sched_barrier(0);
#pragma unroll 8
    for (int kk = 0; kk < 32; ++kk) {
      const float4 w4 = *(const float4*)&wbuf[cur][kk][cc];
      float xr[8];
#pragma unroll
      for (int r = 0; r < 8; ++r) xr[r] = xbuf[cur][rbase + r][kk];
#pragma unroll
      for (int r = 0; r < 8; ++r) {
        acc[r][0] += xr[r] * w4.x;
        acc[r][1] += xr[r] * w4.y;
        acc[r][2] += xr[r] * w4.z;
        acc[r][3] += xr[r] * w4.w;
      }
    }
    asm volatile("" ::: "memory");
    __builtin_amdgcn_s_barrier();         // all reads of buf[cur] done
  }
#undef STAGE

  const float4 as4 = *(const float4*)&a_s[c0 + cc];
  const float4 ad4 = *(const float4*)&a_d[c0 + cc];
  const int head = blockIdx.y * 2 + (cg >> 4);
#pragma unroll
  for (int r = 0; r < 8; ++r) {
    const int row = row0 + rbase + r;
    const bool ok = row < M;
    if (ok) {
      __half2 q0 = __floats2half2_rn(acc[r][0], acc[r][1]);
      __half2 q1 = __floats2half2_rn(acc[r][2], acc[r][3]);
      uint2 qq = make_uint2(*(unsigned*)&q0, *(unsigned*)&q1);
      *(uint2*)&xs16[((size_t)row * HC + c0 + cc) >> 1] = qq;
    }
    float sp = acc[r][0] * as4.x + acc[r][1] * as4.y + acc[r][2] * as4.z + acc[r][3] * as4.w;
    float dp = acc[r][0] * ad4.x + acc[r][1] * ad4.y + acc[r][2] * ad4.z + acc[r][3] * ad4.w;
#pragma unroll
    for (int off = 1; off < 16; off <<= 1) {
      sp += __shfl_xor(sp, off);
      dp += __shfl_xor(dp, off);
    }
    if ((cg & 15) == 0 && ok) {
      asrc[row * NHEAD + head] = sp;
      adst[row * NHEAD + head] = dp;
    }
  }
}

// ============ per-relation alpha_e tables for BOTH layers ============
__global__ __launch_bounds__(256) void relalpha2_kernel(
    const float* __restrict__ rel1, const float* __restrict__ We1, const float* __restrict__ ae1,
    const float* __restrict__ rel2, const float* __restrict__ We2, const float* __restrict__ ae2,
    float* __restrict__ tab1, float* __restrict__ tab2) {
  const int layer = blockIdx.x >> 6;
  const int r = blockIdx.x & 63;
  const float* rel = layer ? rel2 : rel1;
  const float* We  = layer ? We2  : We1;
  const float* ae  = layer ? ae2  : ae1;
  float* tab       = layer ? tab2 : tab1;
  const int K      = layer ? 64   : IN_DIM;
  int t = threadIdx.x;
  float acc = 0.f;
  for (int k = 0; k < K; ++k) acc += rel[(size_t)r * K + k] * We[(size_t)k * HC + t];
  int h = t >> 6, lane = t & 63;
  float p = acc * ae[t];
#pragma unroll
  for (int off = 32; off > 0; off >>= 1) p += __shfl_down(p, off);
  if (lane == 0) tab[r * NHEAD + h] = p;
}

// ============ CSR build ============
__global__ __launch_bounds__(256) void hist_kernel(
    const int* __restrict__ dst, int* __restrict__ deg) {
  int e = blockIdx.x * blockDim.x + threadIdx.x;
  if (e < N_EDGES) atomicAdd(&deg[dst[e]], 1);
}

__global__ __launch_bounds__(256) void block_sum_kernel(
    const int* __restrict__ deg, int* __restrict__ bsum) {
  int i = blockIdx.x * 256 + threadIdx.x;
  int v = (i < N_NODES) ? deg[i] : 0;
#pragma unroll
  for (int off = 32; off > 0; off >>= 1) v += __shfl_down(v, off);
  __shared__ int w[4];
  if ((threadIdx.x & 63) == 0) w[threadIdx.x >> 6] = v;
  __syncthreads();
  if (threadIdx.x == 0) bsum[blockIdx.x] = w[0] + w[1] + w[2] + w[3];
}

__global__ __launch_bounds__(256) void scan_bsum_kernel(
    const int* __restrict__ bsum, int* __restrict__ boff) {
  __shared__ int s[256];
  int t = threadIdx.x;
  int v = (t < SCAN_B) ? bsum[t] : 0;
  s[t] = v;
  __syncthreads();
  for (int off = 1; off < 256; off <<= 1) {
    int u = (t >= off) ? s[t - off] : 0;
    __syncthreads();
    s[t] += u;
    __syncthreads();
  }
  boff[t] = (t == 0) ? 0 : s[t - 1];
}

__global__ __launch_bounds__(256) void scan_final_kernel(
    const int* __restrict__ deg, const int* __restrict__ boff,
    int* __restrict__ rowptr, int* __restrict__ cursor) {
  __shared__ int s[256];
  int t = threadIdx.x;
  int i = blockIdx.x * 256 + t;
  int v = (i < N_NODES) ? deg[i] : 0;
  s[t] = v;
  __syncthreads();
  for (int off = 1; off < 256; off <<= 1) {
    int u = (t >= off) ? s[t - off] : 0;
    __syncthreads();
    s[t] += u;
    __syncthreads();
  }
  int excl = boff[blockIdx.x] + s[t] - v;
  if (i < N_NODES) {
    rowptr[i] = excl;
    cursor[i] = excl;
  }
  if (t == 0 && blockIdx.x == 0) rowptr[N_NODES] = N_EDGES;
}

__global__ __launch_bounds__(256) void fill_kernel(
    const int* __restrict__ src, const int* __restrict__ dst,
    const int* __restrict__ etype, int* __restrict__ cursor,
    int2* __restrict__ csr_pack) {
  int e = blockIdx.x * blockDim.x + threadIdx.x;
  if (e >= N_EDGES) return;
  int d = dst[e];
  int i = atomicAdd(&cursor[d], 1);
  csr_pack[i] = make_int2(src[e], etype[e]);
}

// ============ fused no-max softmax + fp16 gather: ONE WAVE PER NODE ============
__global__ __launch_bounds__(256) void gat_node_kernel(
    const int* __restrict__ rowptr, const int2* __restrict__ csr,
    const float* __restrict__ asrc, const float* __restrict__ adst,
    const float* __restrict__ tab, const __half2* __restrict__ xs16,
    const float* __restrict__ b, float* __restrict__ out, int relu) {
  const int n = (blockIdx.x * blockDim.x + threadIdx.x) >> 6;
  if (n >= N_NODES) return;
  const int lane = threadIdx.x & 63;
  const int hh = lane >> 4;               // head of this lane's 4 cols
  const int cbase = lane << 2;
  const int i0 = rowptr[n], i1 = rowptr[n + 1];
  const float adn = adst[n * NHEAD + hh];
  const float treg = tab[lane * NHEAD + hh];   // lane = rel id (NREL==64)

  float4 acc = make_float4(0.f, 0.f, 0.f, 0.f);
  float den = 0.f;
  int i = i0;
  for (; i + 4 <= i1; i += 4) {
    const int2 p0 = csr[i], p1 = csr[i + 1], p2 = csr[i + 2], p3 = csr[i + 3];
    float l0 = asrc[p0.x * NHEAD + hh] + adn + __shfl(treg, p0.y);
    float l1 = asrc[p1.x * NHEAD + hh] + adn + __shfl(treg, p1.y);
    float l2 = asrc[p2.x * NHEAD + hh] + adn + __shfl(treg, p2.y);
    float l3 = asrc[p3.x * NHEAD + hh] + adn + __shfl(treg, p3.y);
    const uint2 q0 = *(const uint2*)&xs16[((size_t)p0.x * HC + cbase) >> 1];
    const uint2 q1 = *(const uint2*)&xs16[((size_t)p1.x * HC + cbase) >> 1];
    const uint2 q2 = *(const uint2*)&xs16[((size_t)p2.x * HC + cbase) >> 1];
    const uint2 q3 = *(const uint2*)&xs16[((size_t)p3.x * HC + cbase) >> 1];
    l0 = (l0 >= 0.f) ? l0 : NEG_SLOPE * l0;
    l1 = (l1 >= 0.f) ? l1 : NEG_SLOPE * l1;
    l2 = (l2 >= 0.f) ? l2 : NEG_SLOPE * l2;
    l3 = (l3 >= 0.f) ? l3 : NEG_SLOPE * l3;
    const float w0 = __expf(l0), w1 = __expf(l1), w2 = __expf(l2), w3 = __expf(l3);
    den += (w0 + w1) + (w2 + w3);
    const float2 a0 = __half22float2(*(const __half2*)&q0.x), b0 = __half22float2(*(const __half2*)&q0.y);
    const float2 a1 = __half22float2(*(const __half2*)&q1.x), b1 = __half22float2(*(const __half2*)&q1.y);
    const float2 a2 = __half22float2(*(const __half2*)&q2.x), b2 = __half22float2(*(const __half2*)&q2.y);
    const float2 a3 = __half22float2(*(const __half2*)&q3.x), b3 = __half22float2(*(const __half2*)&q3.y);
    acc.x += w0 * a0.x + w1 * a1.x + w2 * a2.x + w3 * a3.x;
    acc.y += w0 * a0.y + w1 * a1.y + w2 * a2.y + w3 * a3.y;
    acc.z += w0 * b0.x + w1 * b1.x + w2 * b2.x + w3 * b3.x;
    acc.w += w0 * b0.y + w1 * b1.y + w2 * b2.y + w3 * b3.y;
  }
  for (; i < i1; ++i) {
    const int2 p = csr[i];
    float l = asrc[p.x * NHEAD + hh] + adn + __shfl(treg, p.y);
    l = (l >= 0.f) ? l : NEG_SLOPE * l;
    const float w = __expf(l);
    const uint2 q = *(const uint2*)&xs16[((size_t)p.x * HC + cbase) >> 1];
    const float2 a = __half22float2(*(const __half2*)&q.x);
    const float2 c = __half22float2(*(const __half2*)&q.y);
    den += w;
    acc.x += w * a.x; acc.y += w * a.y; acc.z += w * c.x; acc.w += w * c.y;
  }

  const float rd = (den > 0.f) ? (0.25f / den) : 0.f;
  float4 y = make_float4(acc.x * rd, acc.y * rd, acc.z * rd, acc.w * rd);
#pragma unroll
  for (int off = 16; off < 64; off <<= 1) {
    y.x += __shfl_xor(y.x, off);
    y.y += __shfl_xor(y.y, off);
    y.z += __shfl_xor(y.z, off);
    y.w += __shfl_xor(y.w, off);
  }
  if (lane < 16) {
    const float4 bb = *(const float4*)&b[lane * 4];
    y.x += bb.x; y.y += bb.y; y.z += bb.z; y.w += bb.w;
    if (relu) {
      y.x = fmaxf(y.x, 0.f); y.y = fmaxf(y.y, 0.f);
      y.z = fmaxf(y.z, 0.f); y.w = fmaxf(y.w, 0.f);
    }
    *(float4*)&out[(size_t)n * 64 + lane * 4] = y;
  }
}

extern "C" void kernel_launch(void* const* d_in, const int* in_sizes, int n_in,
                              void* d_out, int out_size, void* d_ws, size_t ws_size,
                              hipStream_t stream) {
  const float* x   = (const float*)d_in[0];
  const int* eidx  = (const int*)d_in[1];
  const int* etype = (const int*)d_in[2];
  const float* rel1 = (const float*)d_in[3];
  const float* W1   = (const float*)d_in[4];
  const float* We1  = (const float*)d_in[5];
  const float* as1  = (const float*)d_in[6];
  const float* ad1  = (const float*)d_in[7];
  const float* ae1  = (const float*)d_in[8];
  const float* b1   = (const float*)d_in[9];
  const float* rel2 = (const float*)d_in[10];
  const float* W2   = (const float*)d_in[11];
  const float* We2  = (const float*)d_in[12];
  const float* as2  = (const float*)d_in[13];
  const float* ad2  = (const float*)d_in[14];
  const float* ae2  = (const float*)d_in[15];
  const float* b2   = (const float*)d_in[16];
  const int* src = eidx;
  const int* dst = eidx + N_EDGES;

  // ---- workspace layout ----
  __half2* xs16 = (__half2*)d_ws;                         // N*256 halves
  float* fbase = (float*)((char*)d_ws + (size_t)N_NODES * HC * 2);
  float* asrc = fbase;                                    // N*4
  float* adst = asrc + (size_t)N_NODES * NHEAD;           // N*4
  float* tab1 = adst + (size_t)N_NODES * NHEAD;           // R*4
  float* tab2 = tab1 + NREL * NHEAD;                      // R*4
  float* h1   = tab2 + NREL * NHEAD;                      // N*64
  int* ip = (int*)(h1 + (size_t)N_NODES * 64);
  int* deg     = ip;                                      // N
  int* rowptr  = deg + N_NODES;                           // N+1
  int* cursor  = rowptr + N_NODES + 1;                    // N
  int2* csr    = (int2*)(cursor + N_NODES + 1);           // E int2
  int* bsum    = (int*)(csr + N_EDGES);                   // 256
  int* boff    = bsum + 256;                              // 256

  // ---- CSR build + both alpha_e tables (layer-independent) ----
  hipMemsetAsync(deg, 0, N_NODES * sizeof(int), stream);
  hist_kernel<<<(N_EDGES + 255) / 256, 256, 0, stream>>>(dst, deg);
  block_sum_kernel<<<SCAN_B, 256, 0, stream>>>(deg, bsum);
  scan_bsum_kernel<<<1, 256, 0, stream>>>(bsum, boff);
  scan_final_kernel<<<SCAN_B, 256, 0, stream>>>(deg, boff, rowptr, cursor);
  fill_kernel<<<(N_EDGES + 255) / 256, 256, 0, stream>>>(src, dst, etype, cursor, csr);
  relalpha2_kernel<<<2 * NREL, 256, 0, stream>>>(rel1, We1, ae1, rel2, We2, ae2, tab1, tab2);

  const dim3 gemm_grid((N_NODES + 63) / 64, 2);
  const int GB = (N_NODES * 64 + 255) / 256;   // one wave per node

  // ================= layer 1 =================
  gemm_xw_alpha<<<gemm_grid, 256, 0, stream>>>(x, W1, as1, ad1, xs16, asrc, adst, N_NODES, IN_DIM);
  gat_node_kernel<<<GB, 256, 0, stream>>>(rowptr, csr, asrc, adst, tab1, xs16, b1, h1, 1);

  // ================= layer 2 =================
  gemm_xw_alpha<<<gemm_grid, 256, 0, stream>>>(h1, W2, as2, ad2, xs16, asrc, adst, N_NODES, 64);
  gat_node_kernel<<<GB, 256, 0, stream>>>(rowptr, csr, asrc, adst, tab2, xs16, b2, (float*)d_out, 0);
}

// Round 12
// 339.592 us; speedup vs baseline: 1.0541x; 1.0253x over previous
//
#include <hip/hip_runtime.h>
#include <hip/hip_bf16.h>
#include <hip/hip_fp16.h>
#include <math.h>

#define N_NODES 50000
#define N_EDGES 800000
#define IN_DIM 128
#define NHEAD 4
#define NREL 64
#define HC 256              // NHEAD * 64 (both layers: H*HID = H*OUT = 256)
#define NEG_SLOPE 0.2f
#define SCAN_B ((N_NODES + 255) / 256)   // 196 blocks

// async global->LDS, 16B per lane (zero VGPR staging; compiler never auto-emits)
__device__ __forceinline__ void load_lds16(const float* g, float* l) {
  __builtin_amdgcn_global_load_lds(
      (const __attribute__((address_space(1))) unsigned int*)g,
      (__attribute__((address_space(3))) unsigned int*)l, 16, 0, 0);
}

// ============ GEMM + fused alpha, 64x128 tile, BK=16, 8x4/thread ============
// BK=16 halves LDS (48->24 KB) -> ~5-6 blocks/CU instead of 3. R11 showed the
// kernel latency-bound at 16.7% occupancy (VALUBusy 43%); more resident waves
// is the lever. Staging: 3 global_load_lds/wave/stage -> counted vmcnt(3),
// double-buffered, raw s_barrier (vmcnt must NOT drain to 0 in the loop).
__global__ __launch_bounds__(256) void gemm_xw_alpha(
    const float* __restrict__ X, const float* __restrict__ W,
    const float* __restrict__ a_s, const float* __restrict__ a_d,
    __half2* __restrict__ xs16, float* __restrict__ asrc, float* __restrict__ adst,
    int M, int K) {
  __shared__ __align__(16) float wbuf[2][16][128];   // [buf][kk][col] 8KB each
  __shared__ __align__(16) float xbuf[2][64][16];    // [buf][row][kk]  4KB each
  const int t = threadIdx.x;
  const int wv = t >> 6;
  const int l  = t & 63;
  const int rg = l >> 5;                  // row-half within wave
  const int cg = l & 31;                  // col-group
  const int cc = cg * 4;                  // local col
  const int rbase = wv * 16 + rg * 8;     // local row base (8 rows/thread)
  const int row0 = blockIdx.x * 64;
  const int c0 = blockIdx.y * 128;

#define STAGE(BI, KB)                                                          \
  {                                                                            \
    _Pragma("unroll")                                                          \
    for (int j = 0; j < 2; ++j) {                                              \
      const int wrow = wv * 4 + j * 2 + (l >> 5);                              \
      load_lds16(&W[(size_t)((KB) + wrow) * HC + c0 + (l & 31) * 4],           \
                 &wbuf[BI][wv * 4 + j * 2][0]);                                \
    }                                                                          \
    {                                                                          \
      const int xrow = wv * 16 + (l >> 2);                                     \
      const int grow = min(row0 + xrow, M - 1);                                \
      load_lds16(&X[(size_t)grow * K + (KB) + (l & 3) * 4],                    \
                 &xbuf[BI][wv * 16][0]);                                       \
    }                                                                          \
  }

  float acc[8][4];
#pragma unroll
  for (int r = 0; r < 8; ++r)
#pragma unroll
    for (int c = 0; c < 4; ++c) acc[r][c] = 0.f;

  STAGE(0, 0);                            // prologue: tile 0 in flight
  const int nt = K >> 4;
  for (int tg = 0; tg < nt; ++tg) {
    const int cur = tg & 1;
    if (tg + 1 < nt) {
      STAGE(cur ^ 1, (tg + 1) * 16);      // issue next tile (async)
      asm volatile("s_waitcnt vmcnt(3)" ::: "memory");   // this tile landed
    } else {
      asm volatile("s_waitcnt vmcnt(0)" ::: "memory");
    }
    __builtin_amdgcn_s_barrier();         // all waves' tile-tg loads visible
    __builtin_amdgcn_sched_barrier(0);
#pragma unroll
    for (int kk = 0; kk < 16; ++kk) {
      const float4 w4 = *(const float4*)&wbuf[cur][kk][cc];
      float xr[8];
#pragma unroll
      for (int r = 0; r < 8; ++r) xr[r] = xbuf[cur][rbase + r][kk];
#pragma unroll
      for (int r = 0; r < 8; ++r) {
        acc[r][0] += xr[r] * w4.x;
        acc[r][1] += xr[r] * w4.y;
        acc[r][2] += xr[r] * w4.z;
        acc[r][3] += xr[r] * w4.w;
      }
    }
    asm volatile("" ::: "memory");
    __builtin_amdgcn_s_barrier();         // all reads of buf[cur] done
  }
#undef STAGE

  const float4 as4 = *(const float4*)&a_s[c0 + cc];
  const float4 ad4 = *(const float4*)&a_d[c0 + cc];
  const int head = blockIdx.y * 2 + (cg >> 4);
#pragma unroll
  for (int r = 0; r < 8; ++r) {
    const int row = row0 + rbase + r;
    const bool ok = row < M;
    if (ok) {
      __half2 q0 = __floats2half2_rn(acc[r][0], acc[r][1]);
      __half2 q1 = __floats2half2_rn(acc[r][2], acc[r][3]);
      uint2 qq = make_uint2(*(unsigned*)&q0, *(unsigned*)&q1);
      *(uint2*)&xs16[((size_t)row * HC + c0 + cc) >> 1] = qq;
    }
    float sp = acc[r][0] * as4.x + acc[r][1] * as4.y + acc[r][2] * as4.z + acc[r][3] * as4.w;
    float dp = acc[r][0] * ad4.x + acc[r][1] * ad4.y + acc[r][2] * ad4.z + acc[r][3] * ad4.w;
#pragma unroll
    for (int off = 1; off < 16; off <<= 1) {
      sp += __shfl_xor(sp, off);
      dp += __shfl_xor(dp, off);
    }
    if ((cg & 15) == 0 && ok) {
      asrc[row * NHEAD + head] = sp;
      adst[row * NHEAD + head] = dp;
    }
  }
}

// ============ per-relation alpha_e tables for BOTH layers ============
__global__ __launch_bounds__(256) void relalpha2_kernel(
    const float* __restrict__ rel1, const float* __restrict__ We1, const float* __restrict__ ae1,
    const float* __restrict__ rel2, const float* __restrict__ We2, const float* __restrict__ ae2,
    float* __restrict__ tab1, float* __restrict__ tab2) {
  const int layer = blockIdx.x >> 6;
  const int r = blockIdx.x & 63;
  const float* rel = layer ? rel2 : rel1;
  const float* We  = layer ? We2  : We1;
  const float* ae  = layer ? ae2  : ae1;
  float* tab       = layer ? tab2 : tab1;
  const int K      = layer ? 64   : IN_DIM;
  int t = threadIdx.x;
  float acc = 0.f;
  for (int k = 0; k < K; ++k) acc += rel[(size_t)r * K + k] * We[(size_t)k * HC + t];
  int h = t >> 6, lane = t & 63;
  float p = acc * ae[t];
#pragma unroll
  for (int off = 32; off > 0; off >>= 1) p += __shfl_down(p, off);
  if (lane == 0) tab[r * NHEAD + h] = p;
}

// ============ CSR build ============
__global__ __launch_bounds__(256) void hist_kernel(
    const int* __restrict__ dst, int* __restrict__ deg) {
  int e = blockIdx.x * blockDim.x + threadIdx.x;
  if (e < N_EDGES) atomicAdd(&deg[dst[e]], 1);
}

__global__ __launch_bounds__(256) void block_sum_kernel(
    const int* __restrict__ deg, int* __restrict__ bsum) {
  int i = blockIdx.x * 256 + threadIdx.x;
  int v = (i < N_NODES) ? deg[i] : 0;
#pragma unroll
  for (int off = 32; off > 0; off >>= 1) v += __shfl_down(v, off);
  __shared__ int w[4];
  if ((threadIdx.x & 63) == 0) w[threadIdx.x >> 6] = v;
  __syncthreads();
  if (threadIdx.x == 0) bsum[blockIdx.x] = w[0] + w[1] + w[2] + w[3];
}

__global__ __launch_bounds__(256) void scan_bsum_kernel(
    const int* __restrict__ bsum, int* __restrict__ boff) {
  __shared__ int s[256];
  int t = threadIdx.x;
  int v = (t < SCAN_B) ? bsum[t] : 0;
  s[t] = v;
  __syncthreads();
  for (int off = 1; off < 256; off <<= 1) {
    int u = (t >= off) ? s[t - off] : 0;
    __syncthreads();
    s[t] += u;
    __syncthreads();
  }
  boff[t] = (t == 0) ? 0 : s[t - 1];
}

__global__ __launch_bounds__(256) void scan_final_kernel(
    const int* __restrict__ deg, const int* __restrict__ boff,
    int* __restrict__ rowptr, int* __restrict__ cursor) {
  __shared__ int s[256];
  int t = threadIdx.x;
  int i = blockIdx.x * 256 + t;
  int v = (i < N_NODES) ? deg[i] : 0;
  s[t] = v;
  __syncthreads();
  for (int off = 1; off < 256; off <<= 1) {
    int u = (t >= off) ? s[t - off] : 0;
    __syncthreads();
    s[t] += u;
    __syncthreads();
  }
  int excl = boff[blockIdx.x] + s[t] - v;
  if (i < N_NODES) {
    rowptr[i] = excl;
    cursor[i] = excl;
  }
  if (t == 0 && blockIdx.x == 0) rowptr[N_NODES] = N_EDGES;
}

__global__ __launch_bounds__(256) void fill_kernel(
    const int* __restrict__ src, const int* __restrict__ dst,
    const int* __restrict__ etype, int* __restrict__ cursor,
    int2* __restrict__ csr_pack) {
  int e = blockIdx.x * blockDim.x + threadIdx.x;
  if (e >= N_EDGES) return;
  int d = dst[e];
  int i = atomicAdd(&cursor[d], 1);
  csr_pack[i] = make_int2(src[e], etype[e]);
}

// ============ fused no-max softmax + fp16 gather: ONE WAVE PER NODE ============
__global__ __launch_bounds__(256) void gat_node_kernel(
    const int* __restrict__ rowptr, const int2* __restrict__ csr,
    const float* __restrict__ asrc, const float* __restrict__ adst,
    const float* __restrict__ tab, const __half2* __restrict__ xs16,
    const float* __restrict__ b, float* __restrict__ out, int relu) {
  const int n = (blockIdx.x * blockDim.x + threadIdx.x) >> 6;
  if (n >= N_NODES) return;
  const int lane = threadIdx.x & 63;
  const int hh = lane >> 4;               // head of this lane's 4 cols
  const int cbase = lane << 2;
  const int i0 = rowptr[n], i1 = rowptr[n + 1];
  const float adn = adst[n * NHEAD + hh];
  const float treg = tab[lane * NHEAD + hh];   // lane = rel id (NREL==64)

  float4 acc = make_float4(0.f, 0.f, 0.f, 0.f);
  float den = 0.f;
  int i = i0;
  for (; i + 4 <= i1; i += 4) {
    const int2 p0 = csr[i], p1 = csr[i + 1], p2 = csr[i + 2], p3 = csr[i + 3];
    float l0 = asrc[p0.x * NHEAD + hh] + adn + __shfl(treg, p0.y);
    float l1 = asrc[p1.x * NHEAD + hh] + adn + __shfl(treg, p1.y);
    float l2 = asrc[p2.x * NHEAD + hh] + adn + __shfl(treg, p2.y);
    float l3 = asrc[p3.x * NHEAD + hh] + adn + __shfl(treg, p3.y);
    const uint2 q0 = *(const uint2*)&xs16[((size_t)p0.x * HC + cbase) >> 1];
    const uint2 q1 = *(const uint2*)&xs16[((size_t)p1.x * HC + cbase) >> 1];
    const uint2 q2 = *(const uint2*)&xs16[((size_t)p2.x * HC + cbase) >> 1];
    const uint2 q3 = *(const uint2*)&xs16[((size_t)p3.x * HC + cbase) >> 1];
    l0 = (l0 >= 0.f) ? l0 : NEG_SLOPE * l0;
    l1 = (l1 >= 0.f) ? l1 : NEG_SLOPE * l1;
    l2 = (l2 >= 0.f) ? l2 : NEG_SLOPE * l2;
    l3 = (l3 >= 0.f) ? l3 : NEG_SLOPE * l3;
    const float w0 = __expf(l0), w1 = __expf(l1), w2 = __expf(l2), w3 = __expf(l3);
    den += (w0 + w1) + (w2 + w3);
    const float2 a0 = __half22float2(*(const __half2*)&q0.x), b0 = __half22float2(*(const __half2*)&q0.y);
    const float2 a1 = __half22float2(*(const __half2*)&q1.x), b1 = __half22float2(*(const __half2*)&q1.y);
    const float2 a2 = __half22float2(*(const __half2*)&q2.x), b2 = __half22float2(*(const __half2*)&q2.y);
    const float2 a3 = __half22float2(*(const __half2*)&q3.x), b3 = __half22float2(*(const __half2*)&q3.y);
    acc.x += w0 * a0.x + w1 * a1.x + w2 * a2.x + w3 * a3.x;
    acc.y += w0 * a0.y + w1 * a1.y + w2 * a2.y + w3 * a3.y;
    acc.z += w0 * b0.x + w1 * b1.x + w2 * b2.x + w3 * b3.x;
    acc.w += w0 * b0.y + w1 * b1.y + w2 * b2.y + w3 * b3.y;
  }
  for (; i < i1; ++i) {
    const int2 p = csr[i];
    float l = asrc[p.x * NHEAD + hh] + adn + __shfl(treg, p.y);
    l = (l >= 0.f) ? l : NEG_SLOPE * l;
    const float w = __expf(l);
    const uint2 q = *(const uint2*)&xs16[((size_t)p.x * HC + cbase) >> 1];
    const float2 a = __half22float2(*(const __half2*)&q.x);
    const float2 c = __half22float2(*(const __half2*)&q.y);
    den += w;
    acc.x += w * a.x; acc.y += w * a.y; acc.z += w * c.x; acc.w += w * c.y;
  }

  const float rd = (den > 0.f) ? (0.25f / den) : 0.f;
  float4 y = make_float4(acc.x * rd, acc.y * rd, acc.z * rd, acc.w * rd);
#pragma unroll
  for (int off = 16; off < 64; off <<= 1) {
    y.x += __shfl_xor(y.x, off);
    y.y += __shfl_xor(y.y, off);
    y.z += __shfl_xor(y.z, off);
    y.w += __shfl_xor(y.w, off);
  }
  if (lane < 16) {
    const float4 bb = *(const float4*)&b[lane * 4];
    y.x += bb.x; y.y += bb.y; y.z += bb.z; y.w += bb.w;
    if (relu) {
      y.x = fmaxf(y.x, 0.f); y.y = fmaxf(y.y, 0.f);
      y.z = fmaxf(y.z, 0.f); y.w = fmaxf(y.w, 0.f);
    }
    *(float4*)&out[(size_t)n * 64 + lane * 4] = y;
  }
}

extern "C" void kernel_launch(void* const* d_in, const int* in_sizes, int n_in,
                              void* d_out, int out_size, void* d_ws, size_t ws_size,
                              hipStream_t stream) {
  const float* x   = (const float*)d_in[0];
  const int* eidx  = (const int*)d_in[1];
  const int* etype = (const int*)d_in[2];
  const float* rel1 = (const float*)d_in[3];
  const float* W1   = (const float*)d_in[4];
  const float* We1  = (const float*)d_in[5];
  const float* as1  = (const float*)d_in[6];
  const float* ad1  = (const float*)d_in[7];
  const float* ae1  = (const float*)d_in[8];
  const float* b1   = (const float*)d_in[9];
  const float* rel2 = (const float*)d_in[10];
  const float* W2   = (const float*)d_in[11];
  const float* We2  = (const float*)d_in[12];
  const float* as2  = (const float*)d_in[13];
  const float* ad2  = (const float*)d_in[14];
  const float* ae2  = (const float*)d_in[15];
  const float* b2   = (const float*)d_in[16];
  const int* src = eidx;
  const int* dst = eidx + N_EDGES;

  // ---- workspace layout ----
  __half2* xs16 = (__half2*)d_ws;                         // N*256 halves
  float* fbase = (float*)((char*)d_ws + (size_t)N_NODES * HC * 2);
  float* asrc = fbase;                                    // N*4
  float* adst = asrc + (size_t)N_NODES * NHEAD;           // N*4
  float* tab1 = adst + (size_t)N_NODES * NHEAD;           // R*4
  float* tab2 = tab1 + NREL * NHEAD;                      // R*4
  float* h1   = tab2 + NREL * NHEAD;                      // N*64
  int* ip = (int*)(h1 + (size_t)N_NODES * 64);
  int* deg     = ip;                                      // N
  int* rowptr  = deg + N_NODES;                           // N+1
  int* cursor  = rowptr + N_NODES + 1;                    // N
  int2* csr    = (int2*)(cursor + N_NODES + 1);           // E int2
  int* bsum    = (int*)(csr + N_EDGES);                   // 256
  int* boff    = bsum + 256;                              // 256

  // ---- CSR build + both alpha_e tables (layer-independent) ----
  hipMemsetAsync(deg, 0, N_NODES * sizeof(int), stream);
  hist_kernel<<<(N_EDGES + 255) / 256, 256, 0, stream>>>(dst, deg);
  block_sum_kernel<<<SCAN_B, 256, 0, stream>>>(deg, bsum);
  scan_bsum_kernel<<<1, 256, 0, stream>>>(bsum, boff);
  scan_final_kernel<<<SCAN_B, 256, 0, stream>>>(deg, boff, rowptr, cursor);
  fill_kernel<<<(N_EDGES + 255) / 256, 256, 0, stream>>>(src, dst, etype, cursor, csr);
  relalpha2_kernel<<<2 * NREL, 256, 0, stream>>>(rel1, We1, ae1, rel2, We2, ae2, tab1, tab2);

  const dim3 gemm_grid((N_NODES + 63) / 64, 2);
  const int GB = (N_NODES * 64 + 255) / 256;   // one wave per node

  // ================= layer 1 =================
  gemm_xw_alpha<<<gemm_grid, 256, 0, stream>>>(x, W1, as1, ad1, xs16, asrc, adst, N_NODES, IN_DIM);
  gat_node_kernel<<<GB, 256, 0, stream>>>(rowptr, csr, asrc, adst, tab1, xs16, b1, h1, 1);

  // ================= layer 2 =================
  gemm_xw_alpha<<<gemm_grid, 256, 0, stream>>>(h1, W2, as2, ad2, xs16, asrc, adst, N_NODES, 64);
  gat_node_kernel<<<GB, 256, 0, stream>>>(rowptr, csr, asrc, adst, tab2, xs16, b2, (float*)d_out, 0);
}